// Round 1
// baseline (292584.277 us; speedup 1.0000x reference)
//
#include <hip/hip_runtime.h>
#include <stdint.h>

#define T_STEPS 8192
#define IN_DIM  512
#define HID     1024
#define G4      4096

// ---------------------------------------------------------------------------
// Kernel 1: x_gates[t][r] = sum_k input[t][k] * W_ih[r][k] + b_ih[r] + b_hh[r]
// fp32 tiled GEMM (NT), 128x128 tile, K-tile 8, 256 threads, 8x8 per thread.
// ---------------------------------------------------------------------------
__global__ __launch_bounds__(256) void gemm_xgates(
    const float* __restrict__ A,    // [8192][512]
    const float* __restrict__ W,    // [4096][512]
    const float* __restrict__ bih,  // [4096]
    const float* __restrict__ bhh,  // [4096]
    float* __restrict__ xg)         // [8192][4096]
{
    __shared__ float At[8][128];   // k-major A tile
    __shared__ float Bt[8][128];   // k-major W tile
    const int tid = threadIdx.x;
    const int r0 = blockIdx.x * 128;   // gate-row dim (4096)
    const int t0 = blockIdx.y * 128;   // time dim (8192)
    const int tx = tid & 15, ty = tid >> 4;
    const int lrow = tid >> 1;         // 0..127
    const int kq   = (tid & 1) * 4;    // 0 or 4

    float acc[8][8];
#pragma unroll
    for (int i = 0; i < 8; ++i)
#pragma unroll
        for (int j = 0; j < 8; ++j) acc[i][j] = 0.f;

    for (int k0 = 0; k0 < IN_DIM; k0 += 8) {
        float4 av = *(const float4*)&A[(size_t)(t0 + lrow) * IN_DIM + k0 + kq];
        float4 bv = *(const float4*)&W[(size_t)(r0 + lrow) * IN_DIM + k0 + kq];
        __syncthreads();
        At[kq + 0][lrow] = av.x; At[kq + 1][lrow] = av.y;
        At[kq + 2][lrow] = av.z; At[kq + 3][lrow] = av.w;
        Bt[kq + 0][lrow] = bv.x; Bt[kq + 1][lrow] = bv.y;
        Bt[kq + 2][lrow] = bv.z; Bt[kq + 3][lrow] = bv.w;
        __syncthreads();
#pragma unroll
        for (int k = 0; k < 8; ++k) {
            float4 a0 = *(const float4*)&At[k][ty * 8];
            float4 a1 = *(const float4*)&At[k][ty * 8 + 4];
            float4 b0 = *(const float4*)&Bt[k][tx * 8];
            float4 b1 = *(const float4*)&Bt[k][tx * 8 + 4];
            float aa[8] = {a0.x, a0.y, a0.z, a0.w, a1.x, a1.y, a1.z, a1.w};
            float bb[8] = {b0.x, b0.y, b0.z, b0.w, b1.x, b1.y, b1.z, b1.w};
#pragma unroll
            for (int i = 0; i < 8; ++i)
#pragma unroll
                for (int j = 0; j < 8; ++j) acc[i][j] += aa[i] * bb[j];
        }
    }

    float bias[8];
#pragma unroll
    for (int j = 0; j < 8; ++j) {
        int r = r0 + tx * 8 + j;
        bias[j] = bih[r] + bhh[r];
    }
#pragma unroll
    for (int i = 0; i < 8; ++i) {
        int t = t0 + ty * 8 + i;
        float4 o0 = make_float4(acc[i][0] + bias[0], acc[i][1] + bias[1],
                                acc[i][2] + bias[2], acc[i][3] + bias[3]);
        float4 o1 = make_float4(acc[i][4] + bias[4], acc[i][5] + bias[5],
                                acc[i][6] + bias[6], acc[i][7] + bias[7]);
        *(float4*)&xg[(size_t)t * G4 + r0 + tx * 8]     = o0;
        *(float4*)&xg[(size_t)t * G4 + r0 + tx * 8 + 4] = o1;
    }
}

// ---------------------------------------------------------------------------
// Kernel 2: persistent recurrent LSTM.
// 256 blocks x 256 threads (4 waves). Wave w of block b owns h-index
// j = 4*b + w: it computes all 4 gate rows {g*1024 + j}. W_hh slice lives in
// VGPRs (4 rows x 16 floats/lane = 64 VGPRs). No LDS, no __syncthreads in
// the step loop. Cross-block sync: counts[t][b] incremented (release) by each
// wave's lane 0 after storing its h value; consumers spin until all 256
// counters == 4, then acquire-fence and plain-load the h row (L2-cacheable).
// ---------------------------------------------------------------------------
__device__ __forceinline__ float sigm_f(float x) {
    return 1.f / (1.f + __expf(-x));
}
__device__ __forceinline__ float tanh_f(float x) {
    x = fminf(fmaxf(x, -15.f), 15.f);
    float e = __expf(2.f * x);
    return (e - 1.f) / (e + 1.f);
}

__global__ __launch_bounds__(256) void lstm_rec(
    const float* __restrict__ Whh,   // [4096][1024]
    const float* __restrict__ xg,    // [8192][4096]
    float* __restrict__ hs,          // [(T+1)][1024], row 0 pre-zeroed
    uint32_t* __restrict__ counts)   // [T][256], pre-zeroed
{
    const int tid = threadIdx.x;
    const int b   = blockIdx.x;     // 0..255
    const int w   = tid >> 6;       // wave 0..3
    const int l   = tid & 63;       // lane
    const int j   = b * 4 + w;      // owned h index, 0..1023

    // Preload W_hh rows {s*1024 + j} distributed over lanes: lane l holds
    // cols 256*i + 4*l .. +3 for i in 0..3.
    float4 wreg[4][4];
#pragma unroll
    for (int s = 0; s < 4; ++s)
#pragma unroll
        for (int i = 0; i < 4; ++i)
            wreg[s][i] = *(const float4*)&Whh[(size_t)(s * 1024 + j) * HID + 256 * i + 4 * l];

    // Prefetch x-gates for t=0.
    float xv[4];
#pragma unroll
    for (int s = 0; s < 4; ++s)
        xv[s] = xg[(size_t)0 * G4 + s * 1024 + j];

    float c = 0.f;

    for (int t = 0; t < T_STEPS; ++t) {
        if (t > 0) {
            const uint32_t* cn = counts + (size_t)(t - 1) * 256;
            for (;;) {
                uint32_t c0 = __hip_atomic_load(cn + l,       __ATOMIC_RELAXED, __HIP_MEMORY_SCOPE_AGENT);
                uint32_t c1 = __hip_atomic_load(cn + 64 + l,  __ATOMIC_RELAXED, __HIP_MEMORY_SCOPE_AGENT);
                uint32_t c2 = __hip_atomic_load(cn + 128 + l, __ATOMIC_RELAXED, __HIP_MEMORY_SCOPE_AGENT);
                uint32_t c3 = __hip_atomic_load(cn + 192 + l, __ATOMIC_RELAXED, __HIP_MEMORY_SCOPE_AGENT);
                if (__all((c0 == 4u) & (c1 == 4u) & (c2 == 4u) & (c3 == 4u))) break;
            }
            __builtin_amdgcn_fence(__ATOMIC_ACQUIRE, "agent");
        }

        // Load h_{t-1} (row t of hs; row 0 is zeros).
        float4 h4[4];
#pragma unroll
        for (int i = 0; i < 4; ++i)
            h4[i] = *(const float4*)&hs[(size_t)t * HID + 256 * i + 4 * l];

        // Prefetch next step's x-gates (hidden behind compute + next poll).
        float xn[4];
        if (t < T_STEPS - 1) {
#pragma unroll
            for (int s = 0; s < 4; ++s)
                xn[s] = xg[(size_t)(t + 1) * G4 + s * 1024 + j];
        } else {
#pragma unroll
            for (int s = 0; s < 4; ++s) xn[s] = 0.f;
        }

        // Per-lane partial dots for the 4 gate rows.
        float acc[4];
#pragma unroll
        for (int s = 0; s < 4; ++s) {
            float a = 0.f;
#pragma unroll
            for (int i = 0; i < 4; ++i) {
                a = fmaf(wreg[s][i].x, h4[i].x, a);
                a = fmaf(wreg[s][i].y, h4[i].y, a);
                a = fmaf(wreg[s][i].z, h4[i].z, a);
                a = fmaf(wreg[s][i].w, h4[i].w, a);
            }
            acc[s] = a;
        }

        // Wave-wide butterfly reduction (all lanes end with full sums).
#pragma unroll
        for (int off = 1; off < 64; off <<= 1) {
#pragma unroll
            for (int s = 0; s < 4; ++s)
                acc[s] += __shfl_xor(acc[s], off, 64);
        }

        float gi = xv[0] + acc[0];
        float gf = xv[1] + acc[1];
        float gg = xv[2] + acc[2];
        float go = xv[3] + acc[3];

        float ig = sigm_f(gi);
        float fg = sigm_f(gf);
        float gv = tanh_f(gg);
        float og = sigm_f(go);
        c = fg * c + ig * gv;               // every lane keeps identical c
        float h = og * tanh_f(c);

        if (l == 0) {
            hs[(size_t)(t + 1) * HID + j] = h;
            __builtin_amdgcn_fence(__ATOMIC_RELEASE, "agent");
            atomicAdd(&counts[(size_t)t * 256 + b], 1u);
        }

#pragma unroll
        for (int s = 0; s < 4; ++s) xv[s] = xn[s];
    }
}

// ---------------------------------------------------------------------------
// Kernel 3: logits = hs @ W_lin^T + b_lin ; softmax over O=2.
// One wave per timestep row.
// ---------------------------------------------------------------------------
__global__ __launch_bounds__(256) void proj_softmax(
    const float* __restrict__ hs,    // [(T+1)][1024], rows 1..T are h_t
    const float* __restrict__ Wl,    // [2][1024]
    const float* __restrict__ bl,    // [2]
    float* __restrict__ out)         // [T][2]
{
    const int tid = threadIdx.x;
    const int w = tid >> 6, l = tid & 63;
    const int row = blockIdx.x * 4 + w;            // 0..8191
    const float* h = &hs[(size_t)(row + 1) * HID];

    float a0 = 0.f, a1 = 0.f;
#pragma unroll
    for (int i = 0; i < 4; ++i) {
        float4 hv = *(const float4*)&h[256 * i + 4 * l];
        float4 w0 = *(const float4*)&Wl[256 * i + 4 * l];
        float4 w1 = *(const float4*)&Wl[HID + 256 * i + 4 * l];
        a0 = fmaf(hv.x, w0.x, a0); a0 = fmaf(hv.y, w0.y, a0);
        a0 = fmaf(hv.z, w0.z, a0); a0 = fmaf(hv.w, w0.w, a0);
        a1 = fmaf(hv.x, w1.x, a1); a1 = fmaf(hv.y, w1.y, a1);
        a1 = fmaf(hv.z, w1.z, a1); a1 = fmaf(hv.w, w1.w, a1);
    }
#pragma unroll
    for (int off = 1; off < 64; off <<= 1) {
        a0 += __shfl_xor(a0, off, 64);
        a1 += __shfl_xor(a1, off, 64);
    }
    if (l == 0) {
        float l0 = a0 + bl[0];
        float l1 = a1 + bl[1];
        float m  = fmaxf(l0, l1);
        float e0 = __expf(l0 - m), e1 = __expf(l1 - m);
        float inv = 1.f / (e0 + e1);
        float2 o = make_float2(e0 * inv, e1 * inv);
        *(float2*)&out[(size_t)row * 2] = o;
    }
}

// ---------------------------------------------------------------------------
extern "C" void kernel_launch(void* const* d_in, const int* in_sizes, int n_in,
                              void* d_out, int out_size, void* d_ws, size_t ws_size,
                              hipStream_t stream)
{
    const float* input = (const float*)d_in[0];   // [8192][512]
    const float* W_ih  = (const float*)d_in[1];   // [4096][512]
    const float* W_hh  = (const float*)d_in[2];   // [4096][1024]
    const float* b_ih  = (const float*)d_in[3];   // [4096]
    const float* b_hh  = (const float*)d_in[4];   // [4096]
    const float* W_lin = (const float*)d_in[5];   // [2][1024]
    const float* b_lin = (const float*)d_in[6];   // [2]
    float* out = (float*)d_out;                   // [8192][2]

    char* ws = (char*)d_ws;
    float*    hs      = (float*)ws;                          // (T+1)*1024 f32
    size_t    hs_b    = (size_t)(T_STEPS + 1) * HID * sizeof(float);
    uint32_t* counts  = (uint32_t*)(ws + hs_b);              // T*256 u32
    size_t    cnt_b   = (size_t)T_STEPS * 256 * sizeof(uint32_t);
    float*    xg      = (float*)(ws + hs_b + cnt_b);         // T*4096 f32

    // h_0 = 0 (row 0 of hs) and all step counters = 0 (ws is poisoned 0xAA).
    hipMemsetAsync(hs, 0, HID * sizeof(float), stream);
    hipMemsetAsync(counts, 0, cnt_b, stream);

    dim3 g1(G4 / 128, T_STEPS / 128);
    gemm_xgates<<<g1, 256, 0, stream>>>(input, W_ih, b_ih, b_hh, xg);

    lstm_rec<<<256, 256, 0, stream>>>(W_hh, xg, hs, counts);

    proj_softmax<<<T_STEPS / 4, 256, 0, stream>>>(hs, W_lin, b_lin, out);
}

// Round 2
// 27658.862 us; speedup vs baseline: 10.5783x; 10.5783x over previous
//
#include <hip/hip_runtime.h>
#include <stdint.h>

#define T_STEPS 8192
#define IN_DIM  512
#define HID     1024
#define G4      4096

typedef unsigned long long u64;

// ---------------------------------------------------------------------------
// Kernel 1: x_gates[t][r] = sum_k input[t][k] * W_ih[r][k] + b_ih[r] + b_hh[r]
// fp32 tiled GEMM (NT), 128x128 tile, K-tile 8, 256 threads, 8x8 per thread.
// ---------------------------------------------------------------------------
__global__ __launch_bounds__(256) void gemm_xgates(
    const float* __restrict__ A,    // [8192][512]
    const float* __restrict__ W,    // [4096][512]
    const float* __restrict__ bih,  // [4096]
    const float* __restrict__ bhh,  // [4096]
    float* __restrict__ xg)         // [8192][4096]
{
    __shared__ float At[8][128];   // k-major A tile
    __shared__ float Bt[8][128];   // k-major W tile
    const int tid = threadIdx.x;
    const int r0 = blockIdx.x * 128;   // gate-row dim (4096)
    const int t0 = blockIdx.y * 128;   // time dim (8192)
    const int tx = tid & 15, ty = tid >> 4;
    const int lrow = tid >> 1;         // 0..127
    const int kq   = (tid & 1) * 4;    // 0 or 4

    float acc[8][8];
#pragma unroll
    for (int i = 0; i < 8; ++i)
#pragma unroll
        for (int j = 0; j < 8; ++j) acc[i][j] = 0.f;

    for (int k0 = 0; k0 < IN_DIM; k0 += 8) {
        float4 av = *(const float4*)&A[(size_t)(t0 + lrow) * IN_DIM + k0 + kq];
        float4 bv = *(const float4*)&W[(size_t)(r0 + lrow) * IN_DIM + k0 + kq];
        __syncthreads();
        At[kq + 0][lrow] = av.x; At[kq + 1][lrow] = av.y;
        At[kq + 2][lrow] = av.z; At[kq + 3][lrow] = av.w;
        Bt[kq + 0][lrow] = bv.x; Bt[kq + 1][lrow] = bv.y;
        Bt[kq + 2][lrow] = bv.z; Bt[kq + 3][lrow] = bv.w;
        __syncthreads();
#pragma unroll
        for (int k = 0; k < 8; ++k) {
            float4 a0 = *(const float4*)&At[k][ty * 8];
            float4 a1 = *(const float4*)&At[k][ty * 8 + 4];
            float4 b0 = *(const float4*)&Bt[k][tx * 8];
            float4 b1 = *(const float4*)&Bt[k][tx * 8 + 4];
            float aa[8] = {a0.x, a0.y, a0.z, a0.w, a1.x, a1.y, a1.z, a1.w};
            float bb[8] = {b0.x, b0.y, b0.z, b0.w, b1.x, b1.y, b1.z, b1.w};
#pragma unroll
            for (int i = 0; i < 8; ++i)
#pragma unroll
                for (int j = 0; j < 8; ++j) acc[i][j] += aa[i] * bb[j];
        }
    }

    float bias[8];
#pragma unroll
    for (int j = 0; j < 8; ++j) {
        int r = r0 + tx * 8 + j;
        bias[j] = bih[r] + bhh[r];
    }
#pragma unroll
    for (int i = 0; i < 8; ++i) {
        int t = t0 + ty * 8 + i;
        float4 o0 = make_float4(acc[i][0] + bias[0], acc[i][1] + bias[1],
                                acc[i][2] + bias[2], acc[i][3] + bias[3]);
        float4 o1 = make_float4(acc[i][4] + bias[4], acc[i][5] + bias[5],
                                acc[i][6] + bias[6], acc[i][7] + bias[7]);
        *(float4*)&xg[(size_t)t * G4 + r0 + tx * 8]     = o0;
        *(float4*)&xg[(size_t)t * G4 + r0 + tx * 8 + 4] = o1;
    }
}

// ---------------------------------------------------------------------------
// Kernel 2: persistent recurrent LSTM, fence-free.
//
// 256 blocks x 256 threads (4 waves, 1 block/CU). Wave w of block b owns
// h-index j = 4*b + w and computes its 4 gate rows {s*1024 + j}. The W_hh
// slice (4 rows x 16 floats/lane = 64 VGPRs) is register-resident
// (__launch_bounds__(256,1) allows up to 512 VGPRs).
//
// Publication: h_t[j] is a single aligned 8-byte agent-scope relaxed atomic
// word {hi=tag(t+1), lo=f32 bits} in hslot[t&1][j]. The data IS the flag:
// no fences, no cache invalidations, L1/L2 stay warm. Parity double-buffer
// is safe because any h_{t+2} write is transitively ordered after all reads
// of h_t (every h_{t+1} publication required consuming all of h_t).
//
// Poll sharing: wave w polls its quarter (256 words, 4/lane), deposits the
// floats in LDS, __syncthreads, everyone reads the full 1024 from LDS.
// LDS reuse across steps is safe: poll success for step t+1 requires all
// h_t stores, each of which data-depends on that wave's step-t LDS reads.
// ---------------------------------------------------------------------------
__device__ __forceinline__ float sigm_f(float x) {
    return 1.f / (1.f + __expf(-x));
}
__device__ __forceinline__ float tanh_f(float x) {
    x = fminf(fmaxf(x, -15.f), 15.f);
    float e = __expf(2.f * x);
    return (e - 1.f) / (e + 1.f);
}

__global__ __launch_bounds__(256, 1) void lstm_rec(
    const float* __restrict__ Whh,   // [4096][1024]
    const float* __restrict__ xg,    // [8192][4096]
    float* __restrict__ hs,          // [(T+1)][1024], row 0 pre-zeroed
    u64* __restrict__ hslot)         // [2][1024], pre-zeroed (tag 0)
{
    __shared__ float hsh[HID];

    const int tid = threadIdx.x;
    const int b   = blockIdx.x;     // 0..255
    const int w   = tid >> 6;       // wave 0..3
    const int l   = tid & 63;       // lane
    const int j   = b * 4 + w;      // owned h index, 0..1023

    // Register-resident W_hh: lane l holds cols {64*i + l}, i=0..15, for the
    // 4 gate rows s*1024 + j.
    float wreg[4][16];
#pragma unroll
    for (int s = 0; s < 4; ++s)
#pragma unroll
        for (int i = 0; i < 16; ++i)
            wreg[s][i] = Whh[(size_t)(s * 1024 + j) * HID + 64 * i + l];

    // x-gates for t=0.
    float xv[4];
#pragma unroll
    for (int s = 0; s < 4; ++s)
        xv[s] = xg[(size_t)0 * G4 + s * 1024 + j];

    float c = 0.f;

    for (int t = 0; t < T_STEPS; ++t) {
        float hval[16];
        if (t > 0) {
            // Poll our quarter of h_{t-1} (parity (t-1)&1, tag == t).
            const u64* slot = hslot + (((size_t)(t - 1) & 1) << 10) + 256 * w;
            const u64 want = (u64)(uint32_t)t;
            u64 v0, v1, v2, v3;
            for (;;) {
                v0 = __hip_atomic_load(slot + l,       __ATOMIC_RELAXED, __HIP_MEMORY_SCOPE_AGENT);
                v1 = __hip_atomic_load(slot + 64 + l,  __ATOMIC_RELAXED, __HIP_MEMORY_SCOPE_AGENT);
                v2 = __hip_atomic_load(slot + 128 + l, __ATOMIC_RELAXED, __HIP_MEMORY_SCOPE_AGENT);
                v3 = __hip_atomic_load(slot + 192 + l, __ATOMIC_RELAXED, __HIP_MEMORY_SCOPE_AGENT);
                bool ok = ((v0 >> 32) == want) & ((v1 >> 32) == want) &
                          ((v2 >> 32) == want) & ((v3 >> 32) == want);
                if (__all(ok)) break;
            }
            hsh[256 * w + l]       = __uint_as_float((uint32_t)v0);
            hsh[256 * w + 64 + l]  = __uint_as_float((uint32_t)v1);
            hsh[256 * w + 128 + l] = __uint_as_float((uint32_t)v2);
            hsh[256 * w + 192 + l] = __uint_as_float((uint32_t)v3);
            __syncthreads();
#pragma unroll
            for (int i = 0; i < 16; ++i) hval[i] = hsh[64 * i + l];
        } else {
#pragma unroll
            for (int i = 0; i < 16; ++i) hval[i] = 0.f;
        }

        // Prefetch next step's x-gates (overlaps compute + next poll).
        float xn[4] = {0.f, 0.f, 0.f, 0.f};
        if (t < T_STEPS - 1) {
#pragma unroll
            for (int s = 0; s < 4; ++s)
                xn[s] = xg[(size_t)(t + 1) * G4 + s * 1024 + j];
        }

        // 4 gate-row partial dots.
        float acc[4];
#pragma unroll
        for (int s = 0; s < 4; ++s) {
            float a = 0.f;
#pragma unroll
            for (int i = 0; i < 16; ++i) a = fmaf(wreg[s][i], hval[i], a);
            acc[s] = a;
        }
        // Wave butterfly: all lanes end with full sums.
#pragma unroll
        for (int off = 1; off < 64; off <<= 1) {
#pragma unroll
            for (int s = 0; s < 4; ++s)
                acc[s] += __shfl_xor(acc[s], off, 64);
        }

        float ig = sigm_f(xv[0] + acc[0]);
        float fg = sigm_f(xv[1] + acc[1]);
        float gv = tanh_f(xv[2] + acc[2]);
        float og = sigm_f(xv[3] + acc[3]);
        c = fg * c + ig * gv;                // replicated across lanes
        float h = og * tanh_f(c);

        if (l == 0) {
            hs[(size_t)(t + 1) * HID + j] = h;     // for the epilogue kernel
            u64 pub = ((u64)(uint32_t)(t + 1) << 32) | (u64)__float_as_uint(h);
            __hip_atomic_store(&hslot[(((size_t)t & 1) << 10) + j], pub,
                               __ATOMIC_RELAXED, __HIP_MEMORY_SCOPE_AGENT);
        }

#pragma unroll
        for (int s = 0; s < 4; ++s) xv[s] = xn[s];
    }
}

// ---------------------------------------------------------------------------
// Kernel 3: logits = hs @ W_lin^T + b_lin ; softmax over O=2.
// One wave per timestep row.
// ---------------------------------------------------------------------------
__global__ __launch_bounds__(256) void proj_softmax(
    const float* __restrict__ hs,    // [(T+1)][1024], rows 1..T are h_t
    const float* __restrict__ Wl,    // [2][1024]
    const float* __restrict__ bl,    // [2]
    float* __restrict__ out)         // [T][2]
{
    const int tid = threadIdx.x;
    const int w = tid >> 6, l = tid & 63;
    const int row = blockIdx.x * 4 + w;            // 0..8191
    const float* h = &hs[(size_t)(row + 1) * HID];

    float a0 = 0.f, a1 = 0.f;
#pragma unroll
    for (int i = 0; i < 4; ++i) {
        float4 hv = *(const float4*)&h[256 * i + 4 * l];
        float4 w0 = *(const float4*)&Wl[256 * i + 4 * l];
        float4 w1 = *(const float4*)&Wl[HID + 256 * i + 4 * l];
        a0 = fmaf(hv.x, w0.x, a0); a0 = fmaf(hv.y, w0.y, a0);
        a0 = fmaf(hv.z, w0.z, a0); a0 = fmaf(hv.w, w0.w, a0);
        a1 = fmaf(hv.x, w1.x, a1); a1 = fmaf(hv.y, w1.y, a1);
        a1 = fmaf(hv.z, w1.z, a1); a1 = fmaf(hv.w, w1.w, a1);
    }
#pragma unroll
    for (int off = 1; off < 64; off <<= 1) {
        a0 += __shfl_xor(a0, off, 64);
        a1 += __shfl_xor(a1, off, 64);
    }
    if (l == 0) {
        float l0 = a0 + bl[0];
        float l1 = a1 + bl[1];
        float m  = fmaxf(l0, l1);
        float e0 = __expf(l0 - m), e1 = __expf(l1 - m);
        float inv = 1.f / (e0 + e1);
        float2 o = make_float2(e0 * inv, e1 * inv);
        *(float2*)&out[(size_t)row * 2] = o;
    }
}

// ---------------------------------------------------------------------------
extern "C" void kernel_launch(void* const* d_in, const int* in_sizes, int n_in,
                              void* d_out, int out_size, void* d_ws, size_t ws_size,
                              hipStream_t stream)
{
    const float* input = (const float*)d_in[0];   // [8192][512]
    const float* W_ih  = (const float*)d_in[1];   // [4096][512]
    const float* W_hh  = (const float*)d_in[2];   // [4096][1024]
    const float* b_ih  = (const float*)d_in[3];   // [4096]
    const float* b_hh  = (const float*)d_in[4];   // [4096]
    const float* W_lin = (const float*)d_in[5];   // [2][1024]
    const float* b_lin = (const float*)d_in[6];   // [2]
    float* out = (float*)d_out;                   // [8192][2]

    char* ws = (char*)d_ws;
    float* hs     = (float*)ws;                          // (T+1)*1024 f32
    size_t hs_b   = (size_t)(T_STEPS + 1) * HID * sizeof(float);
    u64*   hslot  = (u64*)(ws + hs_b);                   // 2*1024 u64
    size_t slot_b = 2 * 1024 * sizeof(u64);
    float* xg     = (float*)(ws + hs_b + slot_b);        // T*4096 f32

    // h_0 = 0 (row 0 of hs); hslot tags = 0 (ws is poisoned 0xAA each run).
    hipMemsetAsync(hs, 0, HID * sizeof(float), stream);
    hipMemsetAsync(hslot, 0, slot_b, stream);

    dim3 g1(G4 / 128, T_STEPS / 128);
    gemm_xgates<<<g1, 256, 0, stream>>>(input, W_ih, b_ih, b_hh, xg);

    lstm_rec<<<256, 256, 0, stream>>>(W_hh, xg, hs, hslot);

    proj_softmax<<<T_STEPS / 4, 256, 0, stream>>>(hs, W_lin, b_lin, out);
}

// Round 3
// 20953.352 us; speedup vs baseline: 13.9636x; 1.3200x over previous
//
#include <hip/hip_runtime.h>
#include <stdint.h>

#define T_STEPS 8192
#define IN_DIM  512
#define HID     1024
#define G4      4096
#define NBLK    64          // recurrent blocks (<= #CUs, all co-resident)
#define NW      16          // waves per block

typedef unsigned long long u64;

// ---------------------------------------------------------------------------
// Kernel 1: x_gates[t][r] = sum_k input[t][k] * W_ih[r][k] + b_ih[r] + b_hh[r]
// fp32 tiled GEMM (NT), 128x128 tile, K-tile 8, 256 threads, 8x8 per thread.
// ---------------------------------------------------------------------------
__global__ __launch_bounds__(256) void gemm_xgates(
    const float* __restrict__ A,    // [8192][512]
    const float* __restrict__ W,    // [4096][512]
    const float* __restrict__ bih,  // [4096]
    const float* __restrict__ bhh,  // [4096]
    float* __restrict__ xg)         // [8192][4096]
{
    __shared__ float At[8][128];   // k-major A tile
    __shared__ float Bt[8][128];   // k-major W tile
    const int tid = threadIdx.x;
    const int r0 = blockIdx.x * 128;   // gate-row dim (4096)
    const int t0 = blockIdx.y * 128;   // time dim (8192)
    const int tx = tid & 15, ty = tid >> 4;
    const int lrow = tid >> 1;         // 0..127
    const int kq   = (tid & 1) * 4;    // 0 or 4

    float acc[8][8];
#pragma unroll
    for (int i = 0; i < 8; ++i)
#pragma unroll
        for (int j = 0; j < 8; ++j) acc[i][j] = 0.f;

    for (int k0 = 0; k0 < IN_DIM; k0 += 8) {
        float4 av = *(const float4*)&A[(size_t)(t0 + lrow) * IN_DIM + k0 + kq];
        float4 bv = *(const float4*)&W[(size_t)(r0 + lrow) * IN_DIM + k0 + kq];
        __syncthreads();
        At[kq + 0][lrow] = av.x; At[kq + 1][lrow] = av.y;
        At[kq + 2][lrow] = av.z; At[kq + 3][lrow] = av.w;
        Bt[kq + 0][lrow] = bv.x; Bt[kq + 1][lrow] = bv.y;
        Bt[kq + 2][lrow] = bv.z; Bt[kq + 3][lrow] = bv.w;
        __syncthreads();
#pragma unroll
        for (int k = 0; k < 8; ++k) {
            float4 a0 = *(const float4*)&At[k][ty * 8];
            float4 a1 = *(const float4*)&At[k][ty * 8 + 4];
            float4 b0 = *(const float4*)&Bt[k][tx * 8];
            float4 b1 = *(const float4*)&Bt[k][tx * 8 + 4];
            float aa[8] = {a0.x, a0.y, a0.z, a0.w, a1.x, a1.y, a1.z, a1.w};
            float bb[8] = {b0.x, b0.y, b0.z, b0.w, b1.x, b1.y, b1.z, b1.w};
#pragma unroll
            for (int i = 0; i < 8; ++i)
#pragma unroll
                for (int j = 0; j < 8; ++j) acc[i][j] += aa[i] * bb[j];
        }
    }

    float bias[8];
#pragma unroll
    for (int j = 0; j < 8; ++j) {
        int r = r0 + tx * 8 + j;
        bias[j] = bih[r] + bhh[r];
    }
#pragma unroll
    for (int i = 0; i < 8; ++i) {
        int t = t0 + ty * 8 + i;
        float4 o0 = make_float4(acc[i][0] + bias[0], acc[i][1] + bias[1],
                                acc[i][2] + bias[2], acc[i][3] + bias[3]);
        float4 o1 = make_float4(acc[i][4] + bias[4], acc[i][5] + bias[5],
                                acc[i][6] + bias[6], acc[i][7] + bias[7]);
        *(float4*)&xg[(size_t)t * G4 + r0 + tx * 8]     = o0;
        *(float4*)&xg[(size_t)t * G4 + r0 + tx * 8 + 4] = o1;
    }
}

// ---------------------------------------------------------------------------
// Kernel 2: persistent recurrent LSTM, fence-free, low-congestion.
//
// 64 blocks x 1024 threads (16 waves, 1 block/CU). Wave w of block b owns
// h-index j = 16*b + w (4 gate rows {s*1024+j}). W_hh slice register-resident
// (64 VGPRs/lane), pinned with opaque asm so the compiler cannot sink the
// loads back into the loop (R2: VGPR=60 proved it did exactly that).
//
// Publication: block's 16 h values gathered via LDS; wave 0 lanes 0..15 store
// 16 tagged u64 {tag=t+1, f32 h} as ONE coalesced 128B transaction into
// hslot[t&1][...]. 64 store tx/step total.
//
// Observation: waves 0..3 poll one 256-slot quarter each (4 u64/lane,
// coalesced), deposit payload floats into LDS, barrier, everyone reads its
// 16 h values. ~4K LLC tx per sweep chip-wide (vs 32K in R2).
//
// Safety (no fences needed): data-as-flag; parity double-buffer overwrite is
// transitively ordered after all reads of the overwritten generation.
// ---------------------------------------------------------------------------
__device__ __forceinline__ float sigm_f(float x) {
    return 1.f / (1.f + __expf(-x));
}
__device__ __forceinline__ float tanh_f(float x) {
    x = fminf(fmaxf(x, -15.f), 15.f);
    float e = __expf(2.f * x);
    return (e - 1.f) / (e + 1.f);
}

__global__ __launch_bounds__(1024, 1) void lstm_rec(
    const float* __restrict__ Whh,   // [4096][1024]
    const float* __restrict__ xg,    // [8192][4096]
    float* __restrict__ hs,          // [(T+1)][1024], row 0 pre-zeroed
    u64* __restrict__ hslot)         // [2][1024], pre-zeroed (tag 0)
{
    __shared__ float hin[HID];
    __shared__ float hout[NW];

    const int tid = threadIdx.x;
    const int b   = blockIdx.x;          // 0..63
    const int w   = tid >> 6;            // wave 0..15
    const int l   = tid & 63;            // lane
    const int j   = b * NW + w;          // owned h index, 0..1023
    const int ju  = __builtin_amdgcn_readfirstlane(j);   // wave-uniform

    // Register-resident W_hh: lane l holds cols {64*i + l}, i=0..15, for the
    // 4 gate rows s*1024 + j.
    float wreg[4][16];
#pragma unroll
    for (int s = 0; s < 4; ++s)
#pragma unroll
        for (int i = 0; i < 16; ++i)
            wreg[s][i] = Whh[(size_t)(s * 1024 + j) * HID + 64 * i + l];
    // Pin: opaque to the optimizer -> must stay materialized in VGPRs.
#pragma unroll
    for (int s = 0; s < 4; ++s)
#pragma unroll
        for (int i = 0; i < 16; ++i)
            asm volatile("" : "+v"(wreg[s][i]));

    // x-gates for t=0 (wave-uniform scalar loads).
    float xv[4];
#pragma unroll
    for (int s = 0; s < 4; ++s)
        xv[s] = xg[(size_t)0 * G4 + s * 1024 + ju];

    float c = 0.f;

    for (int t = 0; t < T_STEPS; ++t) {
        float hval[16];
        if (t > 0) {
            if (w < 4) {
                // Poll quarter w of h_{t-1}: parity (t-1)&1, want tag == t.
                const u64* slot = hslot + (((size_t)(t - 1) & 1) << 10) + 256 * w;
                const u64 want = (u64)(uint32_t)t;
                u64 v0, v1, v2, v3;
                for (;;) {
                    v0 = __hip_atomic_load(slot + l,       __ATOMIC_RELAXED, __HIP_MEMORY_SCOPE_AGENT);
                    v1 = __hip_atomic_load(slot + 64 + l,  __ATOMIC_RELAXED, __HIP_MEMORY_SCOPE_AGENT);
                    v2 = __hip_atomic_load(slot + 128 + l, __ATOMIC_RELAXED, __HIP_MEMORY_SCOPE_AGENT);
                    v3 = __hip_atomic_load(slot + 192 + l, __ATOMIC_RELAXED, __HIP_MEMORY_SCOPE_AGENT);
                    bool ok = ((v0 >> 32) == want) & ((v1 >> 32) == want) &
                              ((v2 >> 32) == want) & ((v3 >> 32) == want);
                    if (__all(ok)) break;
                }
                hin[256 * w + l]       = __uint_as_float((uint32_t)v0);
                hin[256 * w + 64 + l]  = __uint_as_float((uint32_t)v1);
                hin[256 * w + 128 + l] = __uint_as_float((uint32_t)v2);
                hin[256 * w + 192 + l] = __uint_as_float((uint32_t)v3);
            }
            __syncthreads();
#pragma unroll
            for (int i = 0; i < 16; ++i) hval[i] = hin[64 * i + l];
        } else {
#pragma unroll
            for (int i = 0; i < 16; ++i) hval[i] = 0.f;
        }

        // Prefetch next step's x-gates early (scalar path, lgkmcnt — does not
        // collide with the poll loop's vmcnt waits).
        float xn[4] = {0.f, 0.f, 0.f, 0.f};
        if (t < T_STEPS - 1) {
#pragma unroll
            for (int s = 0; s < 4; ++s)
                xn[s] = xg[(size_t)(t + 1) * G4 + s * 1024 + ju];
        }

        // 4 gate-row partial dots (weights in registers).
        float acc[4];
#pragma unroll
        for (int s = 0; s < 4; ++s) {
            float a = 0.f;
#pragma unroll
            for (int i = 0; i < 16; ++i) a = fmaf(wreg[s][i], hval[i], a);
            acc[s] = a;
        }
        // Wave butterfly: all lanes end with full sums.
#pragma unroll
        for (int off = 1; off < 64; off <<= 1) {
#pragma unroll
            for (int s = 0; s < 4; ++s)
                acc[s] += __shfl_xor(acc[s], off, 64);
        }

        float ig = sigm_f(xv[0] + acc[0]);
        float fg = sigm_f(xv[1] + acc[1]);
        float gv = tanh_f(xv[2] + acc[2]);
        float og = sigm_f(xv[3] + acc[3]);
        c = fg * c + ig * gv;                // replicated across the wave
        float h = og * tanh_f(c);

        if (l == 0) hout[w] = h;
        __syncthreads();

        if (w == 0 && l < NW) {
            float hv = hout[l];
            hs[(size_t)(t + 1) * HID + b * NW + l] = hv;   // for epilogue
            u64 pub = ((u64)(uint32_t)(t + 1) << 32) | (u64)__float_as_uint(hv);
            // 16 lanes x 8B contiguous -> one 128B store transaction.
            __hip_atomic_store(&hslot[(((size_t)t & 1) << 10) + b * NW + l], pub,
                               __ATOMIC_RELAXED, __HIP_MEMORY_SCOPE_AGENT);
        }

#pragma unroll
        for (int s = 0; s < 4; ++s) xv[s] = xn[s];
    }
}

// ---------------------------------------------------------------------------
// Kernel 3: logits = hs @ W_lin^T + b_lin ; softmax over O=2.
// One wave per timestep row.
// ---------------------------------------------------------------------------
__global__ __launch_bounds__(256) void proj_softmax(
    const float* __restrict__ hs,    // [(T+1)][1024], rows 1..T are h_t
    const float* __restrict__ Wl,    // [2][1024]
    const float* __restrict__ bl,    // [2]
    float* __restrict__ out)         // [T][2]
{
    const int tid = threadIdx.x;
    const int w = tid >> 6, l = tid & 63;
    const int row = blockIdx.x * 4 + w;            // 0..8191
    const float* h = &hs[(size_t)(row + 1) * HID];

    float a0 = 0.f, a1 = 0.f;
#pragma unroll
    for (int i = 0; i < 4; ++i) {
        float4 hv = *(const float4*)&h[256 * i + 4 * l];
        float4 w0 = *(const float4*)&Wl[256 * i + 4 * l];
        float4 w1 = *(const float4*)&Wl[HID + 256 * i + 4 * l];
        a0 = fmaf(hv.x, w0.x, a0); a0 = fmaf(hv.y, w0.y, a0);
        a0 = fmaf(hv.z, w0.z, a0); a0 = fmaf(hv.w, w0.w, a0);
        a1 = fmaf(hv.x, w1.x, a1); a1 = fmaf(hv.y, w1.y, a1);
        a1 = fmaf(hv.z, w1.z, a1); a1 = fmaf(hv.w, w1.w, a1);
    }
#pragma unroll
    for (int off = 1; off < 64; off <<= 1) {
        a0 += __shfl_xor(a0, off, 64);
        a1 += __shfl_xor(a1, off, 64);
    }
    if (l == 0) {
        float l0 = a0 + bl[0];
        float l1 = a1 + bl[1];
        float m  = fmaxf(l0, l1);
        float e0 = __expf(l0 - m), e1 = __expf(l1 - m);
        float inv = 1.f / (e0 + e1);
        float2 o = make_float2(e0 * inv, e1 * inv);
        *(float2*)&out[(size_t)row * 2] = o;
    }
}

// ---------------------------------------------------------------------------
extern "C" void kernel_launch(void* const* d_in, const int* in_sizes, int n_in,
                              void* d_out, int out_size, void* d_ws, size_t ws_size,
                              hipStream_t stream)
{
    const float* input = (const float*)d_in[0];   // [8192][512]
    const float* W_ih  = (const float*)d_in[1];   // [4096][512]
    const float* W_hh  = (const float*)d_in[2];   // [4096][1024]
    const float* b_ih  = (const float*)d_in[3];   // [4096]
    const float* b_hh  = (const float*)d_in[4];   // [4096]
    const float* W_lin = (const float*)d_in[5];   // [2][1024]
    const float* b_lin = (const float*)d_in[6];   // [2]
    float* out = (float*)d_out;                   // [8192][2]

    char* ws = (char*)d_ws;
    float* hs     = (float*)ws;                          // (T+1)*1024 f32
    size_t hs_b   = (size_t)(T_STEPS + 1) * HID * sizeof(float);
    u64*   hslot  = (u64*)(ws + hs_b);                   // 2*1024 u64
    size_t slot_b = 2 * 1024 * sizeof(u64);
    float* xg     = (float*)(ws + hs_b + slot_b);        // T*4096 f32

    // h_0 = 0 (row 0 of hs); hslot tags = 0 (ws is poisoned 0xAA each run).
    hipMemsetAsync(hs, 0, HID * sizeof(float), stream);
    hipMemsetAsync(hslot, 0, slot_b, stream);

    dim3 g1(G4 / 128, T_STEPS / 128);
    gemm_xgates<<<g1, 256, 0, stream>>>(input, W_ih, b_ih, b_hh, xg);

    lstm_rec<<<NBLK, NW * 64, 0, stream>>>(W_hh, xg, hs, hslot);

    proj_softmax<<<T_STEPS / 4, 256, 0, stream>>>(hs, W_lin, b_lin, out);
}